// Round 6
// baseline (99.811 us; speedup 1.0000x reference)
//
#include <hip/hip_runtime.h>

#define IN_F 4096
#define OUT_F 11008
#define M_ROWS 64
#define KSPLIT 16
#define GPB 2                       // k-groups per block (32/KSPLIT)
#define NT_BLK 128                  // n-cols per block: 4 waves x 2 strips x 16
#define NBLK_N (OUT_F / NT_BLK)     // 86
#define QZ_WORDS (OUT_F / 8)        // 1376
#define SLICE (M_ROWS * OUT_F)      // 704512 floats per k-split partial

typedef __attribute__((ext_vector_type(8))) short short8;
typedef __attribute__((ext_vector_type(4))) float float4v;

// RNE fp32 -> bf16 (A-side, proven R1/R3/R4/R5)
__device__ __forceinline__ short f2bf(float f) {
    unsigned u = __builtin_bit_cast(unsigned, f);
    return (short)((u + 0x7FFFu + ((u >> 16) & 1u)) >> 16);
}
// truncating fp32 -> bf16 (B-side, proven R3/R4/R5)
__device__ __forceinline__ short f2bf_t(float f) {
    return (short)(__builtin_bit_cast(unsigned, f) >> 16);
}

// ---- pass 1: x [64,4096] fp32 -> xbf2 [512][64][8] bf16 (k-octet-major) ----
__global__ __launch_bounds__(256) void cvt_kernel(const float* __restrict__ x,
                                                  short* __restrict__ xbf2) {
    const int T = blockIdx.x * 256 + threadIdx.x;
    const int u = T >> 6, m = T & 63;
    const float* src = x + m * IN_F + u * 8;
    float4v f0 = *(const float4v*)src;
    float4v f1 = *(const float4v*)(src + 4);
    short8 h;
#pragma unroll
    for (int j = 0; j < 4; ++j) {
        h[j]     = f2bf(f0[j]);
        h[j + 4] = f2bf(f1[j]);
    }
    *(short8*)(xbf2 + T * 8) = h;
}

// ---- pass 2: fused dequant + bf16 MFMA, dbuf LDS, partial stores ----
// launch_bounds(256,4): cap VGPR<=128 so 4 blocks/CU are resident (LDS 4x33KB=132<=160)
__global__ __launch_bounds__(256, 4) void qlin_kernel(
    const short* __restrict__ xbf2,     // [512][64][8] bf16
    const int*   __restrict__ qweight,  // [512, 11008]
    const int*   __restrict__ qzeros,   // [32, 1376]
    const float* __restrict__ scales,   // [32, 11008]
    float* __restrict__ part)           // [KSPLIT][64][11008] partials
{
    __shared__ short lds_a[2][16][64][8];   // 2 x 16 KB A-tiles, [u][m][8]

    const int blk  = blockIdx.x;
    const int nb   = blk % NBLK_N;
    const int kg   = blk / NBLK_N;
    const int t    = threadIdx.x;
    const int wave = t >> 6;
    const int lane = t & 63;
    const int q    = lane >> 4;
    const int nl   = lane & 15;
    const int n0   = nb * NT_BLK + wave * 32 + nl;
    const int n1   = n0 + 16;
    const int shz  = (n0 & 7) * 4;      // same for n1
    const int g0   = kg * GPB;

    float4v acc0[4], acc1[4];
#pragma unroll
    for (int i = 0; i < 4; ++i) {
        acc0[i] = (float4v){0.f, 0.f, 0.f, 0.f};
        acc1[i] = (float4v){0.f, 0.f, 0.f, 0.f};
    }

#define STAGE(buf, g)                                                          \
    {                                                                          \
        _Pragma("unroll")                                                      \
        for (int i_ = 0; i_ < 4; ++i_) {                                       \
            const int u_ = wave * 4 + i_;                                      \
            const short* gsrc_ = xbf2 + (((g) * 16 + u_) * 64 + lane) * 8;     \
            __builtin_amdgcn_global_load_lds(                                  \
                (const __attribute__((address_space(1))) void*)gsrc_,          \
                (__attribute__((address_space(3))) void*)&lds_a[buf][u_][0][0],\
                16, 0, 0);                                                     \
        }                                                                      \
    }

#define LOAD_META(g, qw, zw0, zw1, s0v, s1v)                                   \
    {                                                                          \
        _Pragma("unroll")                                                      \
        for (int kk_ = 0; kk_ < 4; ++kk_) {                                    \
            const int row_ = (g) * 16 + kk_ * 4 + q;                           \
            qw[kk_]     = qweight[row_ * OUT_F + n0];                          \
            qw[kk_ + 4] = qweight[row_ * OUT_F + n1];                          \
        }                                                                      \
        zw0 = qzeros[(g) * QZ_WORDS + (n0 >> 3)];                              \
        zw1 = qzeros[(g) * QZ_WORDS + (n1 >> 3)];                              \
        s0v = scales[(g) * OUT_F + n0];                                        \
        s1v = scales[(g) * OUT_F + n1];                                        \
    }

    int qwc[8], zc0, zc1;
    float sc0, sc1;
    STAGE(0, g0);
    LOAD_META(g0, qwc, zc0, zc1, sc0, sc1);

#pragma unroll
    for (int gi = 0; gi < GPB; ++gi) {
        __syncthreads();   // buf[gi&1] + current meta ready

        int qwn[8], zn0, zn1;
        float sn0, sn1;
        if (gi + 1 < GPB) {
            STAGE((gi + 1) & 1, g0 + gi + 1);             // DMA next tile
            LOAD_META(g0 + gi + 1, qwn, zn0, zn1, sn0, sn1);
        }

        const float s0  = sc0, s1 = sc1;
        const float nz0 = -s0 * (float)(((zc0 >> shz) & 15) + 1);
        const float nz1 = -s1 * (float)(((zc1 >> shz) & 15) + 1);

#pragma unroll
        for (int kk = 0; kk < 4; ++kk) {
            short8 b0, b1;
#pragma unroll
            for (int j = 0; j < 8; ++j) {
                b0[j] = f2bf_t(fmaf(s0, (float)((qwc[kk] >> (4 * j)) & 15), nz0));
                b1[j] = f2bf_t(fmaf(s1, (float)((qwc[kk + 4] >> (4 * j)) & 15), nz1));
            }
            const int u = kk * 4 + q;
#pragma unroll
            for (int mt = 0; mt < 4; ++mt) {
                short8 a = *(const short8*)&lds_a[gi & 1][u][mt * 16 + nl][0];
                acc0[mt] = __builtin_amdgcn_mfma_f32_16x16x32_bf16(a, b0, acc0[mt], 0, 0, 0);
                acc1[mt] = __builtin_amdgcn_mfma_f32_16x16x32_bf16(a, b1, acc1[mt], 0, 0, 0);
            }
        }

        if (gi + 1 < GPB) {
#pragma unroll
            for (int i = 0; i < 8; ++i) qwc[i] = qwn[i];
            zc0 = zn0; zc1 = zn1; sc0 = sn0; sc1 = sn1;
        }
    }

    // epilogue: plain coalesced stores to this split's partial slice
    float* myp = part + kg * SLICE;
#pragma unroll
    for (int mt = 0; mt < 4; ++mt) {
#pragma unroll
        for (int r = 0; r < 4; ++r) {
            const int m = mt * 16 + q * 4 + r;
            myp[m * OUT_F + n0] = acc0[mt][r];
            myp[m * OUT_F + n1] = acc1[mt][r];
        }
    }
#undef STAGE
#undef LOAD_META
}

// ---- pass 3: sum KSPLIT partial slices + bias -> out ----
__global__ __launch_bounds__(256) void reduce_kernel(
    const float* __restrict__ part, const float* __restrict__ bias,
    float* __restrict__ out) {
    const int i4 = (blockIdx.x * 256 + threadIdx.x) * 4;
    const int n  = i4 % OUT_F;   // OUT_F % 4 == 0: float4 stays within a row
    float4v s = *(const float4v*)(bias + n);
#pragma unroll
    for (int kg = 0; kg < KSPLIT; ++kg)
        s += *(const float4v*)(part + kg * SLICE + i4);
    *(float4v*)(out + i4) = s;
}

extern "C" void kernel_launch(void* const* d_in, const int* in_sizes, int n_in,
                              void* d_out, int out_size, void* d_ws, size_t ws_size,
                              hipStream_t stream) {
    const float* x       = (const float*)d_in[0];
    const int*   qweight = (const int*)d_in[1];
    const int*   qzeros  = (const int*)d_in[2];
    const float* scales  = (const float*)d_in[3];
    // d_in[4] = g_idx (structurally k/128; unused)
    const float* bias    = (const float*)d_in[5];
    float* out = (float*)d_out;

    short* xbf2 = (short*)d_ws;                               // 512 KB
    float* part = (float*)((char*)d_ws + (1 << 20));          // 45 MB @ +1 MB

    cvt_kernel<<<dim3((IN_F / 8) * M_ROWS / 256), dim3(256), 0, stream>>>(x, xbf2);
    qlin_kernel<<<dim3(NBLK_N * KSPLIT), dim3(256), 0, stream>>>(
        xbf2, qweight, qzeros, scales, part);
    reduce_kernel<<<dim3(SLICE / 4 / 256), dim3(256), 0, stream>>>(part, bias, out);
}

// Round 7
// 95.908 us; speedup vs baseline: 1.0407x; 1.0407x over previous
//
#include <hip/hip_runtime.h>

#define IN_F 4096
#define OUT_F 11008
#define M_ROWS 64
#define KSPLIT 8
#define GPB 4                       // k-groups per block (32/KSPLIT)
#define NT_BLK 128                  // n-cols per block: 4 waves x 2 strips x 16
#define NBLK_N (OUT_F / NT_BLK)     // 86 -> grid 688, all co-resident at 3 blk/CU
#define QZ_WORDS (OUT_F / 8)        // 1376
#define SLICE (M_ROWS * OUT_F)      // 704512 elements per k-split partial

typedef __attribute__((ext_vector_type(8))) short short8;
typedef __attribute__((ext_vector_type(4))) float float4v;

// RNE fp32 -> bf16 (proven R1/R3-R6)
__device__ __forceinline__ short f2bf(float f) {
    unsigned u = __builtin_bit_cast(unsigned, f);
    return (short)((u + 0x7FFFu + ((u >> 16) & 1u)) >> 16);
}
// truncating fp32 -> bf16 (B-side, proven R3-R6)
__device__ __forceinline__ short f2bf_t(float f) {
    return (short)(__builtin_bit_cast(unsigned, f) >> 16);
}
__device__ __forceinline__ float bf2f(short h) {
    return __builtin_bit_cast(float, ((unsigned)(unsigned short)h) << 16);
}

// ---- pass 1: x [64,4096] fp32 -> xbf2 [512][64][8] bf16 (k-octet-major) ----
__global__ __launch_bounds__(256) void cvt_kernel(const float* __restrict__ x,
                                                  short* __restrict__ xbf2) {
    const int T = blockIdx.x * 256 + threadIdx.x;
    const int u = T >> 6, m = T & 63;
    const float* src = x + m * IN_F + u * 8;
    float4v f0 = *(const float4v*)src;
    float4v f1 = *(const float4v*)(src + 4);
    short8 h;
#pragma unroll
    for (int j = 0; j < 4; ++j) {
        h[j]     = f2bf(f0[j]);
        h[j + 4] = f2bf(f1[j]);
    }
    *(short8*)(xbf2 + T * 8) = h;
}

// ---- pass 2: fused dequant + bf16 MFMA. NO LDS, NO barriers. ----
// A fragments loaded straight from xbf2 (L1/L2-resident); waves free-run.
__global__ __launch_bounds__(256, 3) void qlin_kernel(
    const short* __restrict__ xbf2,     // [512][64][8] bf16
    const int*   __restrict__ qweight,  // [512, 11008]
    const int*   __restrict__ qzeros,   // [32, 1376]
    const float* __restrict__ scales,   // [32, 11008]
    short* __restrict__ part)           // [KSPLIT][64][11008] bf16 partials
{
    const int blk  = blockIdx.x;
    const int nb   = blk % NBLK_N;
    const int kg   = blk / NBLK_N;
    const int t    = threadIdx.x;
    const int wave = t >> 6;
    const int lane = t & 63;
    const int q    = lane >> 4;
    const int nl   = lane & 15;
    const int n0   = nb * NT_BLK + wave * 32 + nl;
    const int n1   = n0 + 16;
    const int shz  = (n0 & 7) * 4;      // same for n1
    const int g0   = kg * GPB;

    float4v acc0[4], acc1[4];
#pragma unroll
    for (int i = 0; i < 4; ++i) {
        acc0[i] = (float4v){0.f, 0.f, 0.f, 0.f};
        acc1[i] = (float4v){0.f, 0.f, 0.f, 0.f};
    }

    // per-lane A base: chunk index (g*16+u)*64 + (mt*16+nl), 16 B each
    const short* abase_nl = xbf2 + nl * 8;

#pragma unroll
    for (int gi = 0; gi < GPB; ++gi) {
        const int g = g0 + gi;

        int qw[8];
#pragma unroll
        for (int kk = 0; kk < 4; ++kk) {
            const int row = g * 16 + kk * 4 + q;
            qw[kk]     = qweight[row * OUT_F + n0];
            qw[kk + 4] = qweight[row * OUT_F + n1];
        }
        const float s0  = scales[g * OUT_F + n0];
        const float s1  = scales[g * OUT_F + n1];
        const float nz0 = -s0 * (float)(((qzeros[g * QZ_WORDS + (n0 >> 3)] >> shz) & 15) + 1);
        const float nz1 = -s1 * (float)(((qzeros[g * QZ_WORDS + (n1 >> 3)] >> shz) & 15) + 1);

#pragma unroll
        for (int kk = 0; kk < 4; ++kk) {
            short8 b0, b1;
#pragma unroll
            for (int j = 0; j < 8; ++j) {
                b0[j] = f2bf_t(fmaf(s0, (float)((qw[kk] >> (4 * j)) & 15), nz0));
                b1[j] = f2bf_t(fmaf(s1, (float)((qw[kk + 4] >> (4 * j)) & 15), nz1));
            }
            const int u = kk * 4 + q;
            const short* abase = abase_nl + (g * 16 + u) * 64 * 8;
#pragma unroll
            for (int mt = 0; mt < 4; ++mt) {
                short8 a = *(const short8*)(abase + mt * 16 * 8);
                acc0[mt] = __builtin_amdgcn_mfma_f32_16x16x32_bf16(a, b0, acc0[mt], 0, 0, 0);
                acc1[mt] = __builtin_amdgcn_mfma_f32_16x16x32_bf16(a, b1, acc1[mt], 0, 0, 0);
            }
        }
    }

    // epilogue: bf16 (RNE) partial stores, coalesced 32 B per quad
    short* myp = part + kg * SLICE;
#pragma unroll
    for (int mt = 0; mt < 4; ++mt) {
#pragma unroll
        for (int r = 0; r < 4; ++r) {
            const int m = mt * 16 + q * 4 + r;
            myp[m * OUT_F + n0] = f2bf(acc0[mt][r]);
            myp[m * OUT_F + n1] = f2bf(acc1[mt][r]);
        }
    }
}

// ---- pass 3: sum KSPLIT bf16 partial slices + bias -> fp32 out ----
__global__ __launch_bounds__(256) void reduce_kernel(
    const short* __restrict__ part, const float* __restrict__ bias,
    float* __restrict__ out) {
    const int i8 = (blockIdx.x * 256 + threadIdx.x) * 8;
    const int n  = i8 % OUT_F;   // OUT_F % 8 == 0: stays within one row
    float s[8];
#pragma unroll
    for (int j = 0; j < 8; ++j) s[j] = bias[n + j];
#pragma unroll
    for (int kg = 0; kg < KSPLIT; ++kg) {
        short8 p = *(const short8*)(part + kg * SLICE + i8);
#pragma unroll
        for (int j = 0; j < 8; ++j) s[j] += bf2f(p[j]);
    }
    *(float4v*)(out + i8)     = (float4v){s[0], s[1], s[2], s[3]};
    *(float4v*)(out + i8 + 4) = (float4v){s[4], s[5], s[6], s[7]};
}

extern "C" void kernel_launch(void* const* d_in, const int* in_sizes, int n_in,
                              void* d_out, int out_size, void* d_ws, size_t ws_size,
                              hipStream_t stream) {
    const float* x       = (const float*)d_in[0];
    const int*   qweight = (const int*)d_in[1];
    const int*   qzeros  = (const int*)d_in[2];
    const float* scales  = (const float*)d_in[3];
    // d_in[4] = g_idx (structurally k/128; unused)
    const float* bias    = (const float*)d_in[5];
    float* out = (float*)d_out;

    short* xbf2 = (short*)d_ws;                        // 512 KB
    short* part = (short*)((char*)d_ws + (1 << 20));   // 11.25 MB @ +1 MB

    cvt_kernel<<<dim3((IN_F / 8) * M_ROWS / 256), dim3(256), 0, stream>>>(x, xbf2);
    qlin_kernel<<<dim3(NBLK_N * KSPLIT), dim3(256), 0, stream>>>(
        xbf2, qweight, qzeros, scales, part);
    reduce_kernel<<<dim3(SLICE / 8 / 256), dim3(256), 0, stream>>>(part, bias, out);
}

// Round 8
// 95.800 us; speedup vs baseline: 1.0419x; 1.0011x over previous
//
#include <hip/hip_runtime.h>

#define IN_F 4096
#define OUT_F 11008
#define M_ROWS 64
#define KSPLIT 8
#define GPB 4                       // k-groups per block (32/KSPLIT)
#define NT_BLK 128                  // n-cols per block: 4 waves x 2 strips x 16
#define NBLK_N (OUT_F / NT_BLK)     // 86 -> grid 688
#define QZ_WORDS (OUT_F / 8)        // 1376
#define SLICE (M_ROWS * OUT_F)      // 704512 elements per k-split partial

typedef __attribute__((ext_vector_type(8))) short short8;
typedef __attribute__((ext_vector_type(4))) float float4v;

// RNE fp32 -> bf16 (proven R1/R3-R7)
__device__ __forceinline__ short f2bf(float f) {
    unsigned u = __builtin_bit_cast(unsigned, f);
    return (short)((u + 0x7FFFu + ((u >> 16) & 1u)) >> 16);
}
// truncating fp32 -> bf16 (B-side, proven R3-R7)
__device__ __forceinline__ short f2bf_t(float f) {
    return (short)(__builtin_bit_cast(unsigned, f) >> 16);
}
__device__ __forceinline__ float bf2f(short h) {
    return __builtin_bit_cast(float, ((unsigned)(unsigned short)h) << 16);
}

// ---- pass 1: x [64,4096] fp32 -> xbf2 [512][64][8] bf16 (k-octet-major) ----
__global__ __launch_bounds__(256) void cvt_kernel(const float* __restrict__ x,
                                                  short* __restrict__ xbf2) {
    const int T = blockIdx.x * 256 + threadIdx.x;
    const int u = T >> 6, m = T & 63;
    const float* src = x + m * IN_F + u * 8;
    float4v f0 = *(const float4v*)src;
    float4v f1 = *(const float4v*)(src + 4);
    short8 h;
#pragma unroll
    for (int j = 0; j < 4; ++j) {
        h[j]     = f2bf(f0[j]);
        h[j + 4] = f2bf(f1[j]);
    }
    *(short8*)(xbf2 + T * 8) = h;
}

// ---- pass 2: fused dequant + bf16 MFMA. No LDS/barriers. ----
// Phase 1 issues ALL qweight/meta loads (40 VMEM in flight) before any use:
// one miss-latency for the whole block, not one per group.
__global__ __launch_bounds__(256, 3) void qlin_kernel(
    const short* __restrict__ xbf2,     // [512][64][8] bf16
    const int*   __restrict__ qweight,  // [512, 11008]
    const int*   __restrict__ qzeros,   // [32, 1376]
    const float* __restrict__ scales,   // [32, 11008]
    short* __restrict__ part)           // [KSPLIT][64][11008] bf16 partials
{
    const int blk  = blockIdx.x;
    const int nb   = blk % NBLK_N;
    const int kg   = blk / NBLK_N;
    const int t    = threadIdx.x;
    const int wave = t >> 6;
    const int lane = t & 63;
    const int q    = lane >> 4;
    const int nl   = lane & 15;
    const int n0   = nb * NT_BLK + wave * 32 + nl;
    const int n1   = n0 + 16;
    const int shz  = (n0 & 7) * 4;      // same for n1
    const int g0   = kg * GPB;

    // ---------------- phase 1: issue every global load up front ----------------
    int   qw[GPB * 8];        // [gi][strip*4 + kk]
    int   zr0[GPB], zr1[GPB];
    float s0a[GPB], s1a[GPB];
#pragma unroll
    for (int gi = 0; gi < GPB; ++gi) {
        const int g = g0 + gi;
#pragma unroll
        for (int kk = 0; kk < 4; ++kk) {
            const int row = g * 16 + kk * 4 + q;
            qw[gi * 8 + kk]     = qweight[row * OUT_F + n0];
            qw[gi * 8 + kk + 4] = qweight[row * OUT_F + n1];
        }
        zr0[gi] = qzeros[g * QZ_WORDS + (n0 >> 3)];
        zr1[gi] = qzeros[g * QZ_WORDS + (n1 >> 3)];
        s0a[gi] = scales[g * OUT_F + n0];
        s1a[gi] = scales[g * OUT_F + n1];
    }

    float4v acc0[4], acc1[4];
#pragma unroll
    for (int i = 0; i < 4; ++i) {
        acc0[i] = (float4v){0.f, 0.f, 0.f, 0.f};
        acc1[i] = (float4v){0.f, 0.f, 0.f, 0.f};
    }

    const short* abase_nl = xbf2 + nl * 8;

    // ---------------- phase 2: dequant + MFMA ----------------
#pragma unroll
    for (int gi = 0; gi < GPB; ++gi) {
        const int g = g0 + gi;
        const float s0  = s0a[gi];
        const float s1  = s1a[gi];
        const float nz0 = -s0 * (float)(((zr0[gi] >> shz) & 15) + 1);
        const float nz1 = -s1 * (float)(((zr1[gi] >> shz) & 15) + 1);

#pragma unroll
        for (int kk = 0; kk < 4; ++kk) {
            const int w0 = qw[gi * 8 + kk];
            const int w1 = qw[gi * 8 + kk + 4];
            short8 b0, b1;
#pragma unroll
            for (int j = 0; j < 8; ++j) {
                b0[j] = f2bf_t(fmaf(s0, (float)((w0 >> (4 * j)) & 15), nz0));
                b1[j] = f2bf_t(fmaf(s1, (float)((w1 >> (4 * j)) & 15), nz1));
            }
            const int u = kk * 4 + q;
            const short* abase = abase_nl + (g * 16 + u) * 64 * 8;
#pragma unroll
            for (int mt = 0; mt < 4; ++mt) {
                short8 a = *(const short8*)(abase + mt * 16 * 8);
                acc0[mt] = __builtin_amdgcn_mfma_f32_16x16x32_bf16(a, b0, acc0[mt], 0, 0, 0);
                acc1[mt] = __builtin_amdgcn_mfma_f32_16x16x32_bf16(a, b1, acc1[mt], 0, 0, 0);
            }
        }
    }

    // epilogue: bf16 (RNE) partial stores
    short* myp = part + kg * SLICE;
#pragma unroll
    for (int mt = 0; mt < 4; ++mt) {
#pragma unroll
        for (int r = 0; r < 4; ++r) {
            const int m = mt * 16 + q * 4 + r;
            myp[m * OUT_F + n0] = f2bf(acc0[mt][r]);
            myp[m * OUT_F + n1] = f2bf(acc1[mt][r]);
        }
    }
}

// ---- pass 3: sum KSPLIT bf16 partial slices + bias -> fp32 out ----
__global__ __launch_bounds__(256) void reduce_kernel(
    const short* __restrict__ part, const float* __restrict__ bias,
    float* __restrict__ out) {
    const int i8 = (blockIdx.x * 256 + threadIdx.x) * 8;
    const int n  = i8 % OUT_F;   // OUT_F % 8 == 0: stays within one row
    float s[8];
#pragma unroll
    for (int j = 0; j < 8; ++j) s[j] = bias[n + j];
#pragma unroll
    for (int kg = 0; kg < KSPLIT; ++kg) {
        short8 p = *(const short8*)(part + kg * SLICE + i8);
#pragma unroll
        for (int j = 0; j < 8; ++j) s[j] += bf2f(p[j]);
    }
    *(float4v*)(out + i8)     = (float4v){s[0], s[1], s[2], s[3]};
    *(float4v*)(out + i8 + 4) = (float4v){s[4], s[5], s[6], s[7]};
}

extern "C" void kernel_launch(void* const* d_in, const int* in_sizes, int n_in,
                              void* d_out, int out_size, void* d_ws, size_t ws_size,
                              hipStream_t stream) {
    const float* x       = (const float*)d_in[0];
    const int*   qweight = (const int*)d_in[1];
    const int*   qzeros  = (const int*)d_in[2];
    const float* scales  = (const float*)d_in[3];
    // d_in[4] = g_idx (structurally k/128; unused)
    const float* bias    = (const float*)d_in[5];
    float* out = (float*)d_out;

    short* xbf2 = (short*)d_ws;                        // 512 KB
    short* part = (short*)((char*)d_ws + (1 << 20));   // 11.25 MB @ +1 MB

    cvt_kernel<<<dim3((IN_F / 8) * M_ROWS / 256), dim3(256), 0, stream>>>(x, xbf2);
    qlin_kernel<<<dim3(NBLK_N * KSPLIT), dim3(256), 0, stream>>>(
        xbf2, qweight, qzeros, scales, part);
    reduce_kernel<<<dim3(SLICE / 8 / 256), dim3(256), 0, stream>>>(part, bias, out);
}